// Round 5
// baseline (293.606 us; speedup 1.0000x reference)
//
#include <hip/hip_runtime.h>
#include <hip/hip_bf16.h>
#include <stdint.h>

// ---------------------------------------------------------------------------
// Self-attention, single head, d=1024, seq=2048, batch=4, fp32 in/out.
// R5: 3 dispatches. Casts fused into qkv staging (fp32 -> cvt -> ds_write;
//     no xb/wcat buffers). s_exp and pv move to BK=64 (half the barriers).
// Pipeline: QKV = x @ [Wq|Wk|Wv]^T (fp32 in, Q scaled 1/32, V transposed) |
//           S = exp(QK^T) + rowsum partials | O = (P Vt^T) / rowsum
// Workspace (81 MiB): Q @ 0 (16)  K @ 16 (16)  Vt @ 32 (16)  S @ 48 (32)  part @ 80 (1)
// ---------------------------------------------------------------------------

typedef __attribute__((ext_vector_type(8))) short bf16x8;   // 8 bf16 = 4 VGPRs
typedef __attribute__((ext_vector_type(4))) float f32x4;

__device__ __forceinline__ void async_copy16(const void* g, void* l) {
  __builtin_amdgcn_global_load_lds(
      (__attribute__((address_space(1))) void*)(g),
      (__attribute__((address_space(3))) void*)(l),
      16, 0, 0);
}

__device__ __forceinline__ bf16x8 cvt8(const float* __restrict__ p) {
  const float4 f0 = ((const float4*)p)[0];
  const float4 f1 = ((const float4*)p)[1];
  union { bf16x8 v; __hip_bfloat16 h[8]; } r;
  r.h[0] = __float2bfloat16(f0.x); r.h[1] = __float2bfloat16(f0.y);
  r.h[2] = __float2bfloat16(f0.z); r.h[3] = __float2bfloat16(f0.w);
  r.h[4] = __float2bfloat16(f1.x); r.h[5] = __float2bfloat16(f1.y);
  r.h[6] = __float2bfloat16(f1.z); r.h[7] = __float2bfloat16(f1.w);
  return r.v;
}

// ---------------- fused QKV projection, fp32 inputs ----------------
// X [8192,1024] f32; W* [1024,1024] f32. Q,K -> [8192,1024] bf16 (Q/32);
// V -> Vt [4][1024][2048] bf16 via scattered 8B stores.
__global__ __launch_bounds__(256)
void gemm_qkv(const float* __restrict__ X,
              const float* __restrict__ Wq,
              const float* __restrict__ Wk,
              const float* __restrict__ Wv,
              __hip_bfloat16* __restrict__ Q,
              __hip_bfloat16* __restrict__ Kk,
              __hip_bfloat16* __restrict__ Vt)
{
  __shared__ __align__(16) __hip_bfloat16 As[128 * 32];
  __shared__ __align__(16) __hip_bfloat16 Bs[128 * 32];

  const int K = 1024;
  const long long tile_m = (long long)blockIdx.y * 128;
  const long long tile_n = (long long)blockIdx.x * 128;
  const int mat   = (int)(tile_n >> 10);
  const int coln0 = (int)(tile_n & 1023);
  const float* Wsel = (mat == 0) ? Wq : (mat == 1) ? Wk : Wv;

  const int tid  = threadIdx.x;
  const int wid  = tid >> 6;
  const int lane = tid & 63;

  const int srow = wid * 16 + (lane >> 2);   // staging row (of 64-row half)
  const int scol = (lane & 3) * 8;           // staging col (8 elements)

  const float* ap = X    + ((long long)(tile_m + srow)) * K + scol;
  const float* bp = Wsel + ((long long)(coln0  + srow)) * K + scol;

  const int wm   = (wid >> 1) * 64;
  const int wn   = (wid & 1) * 64;
  const int quad = lane >> 4;
  const int l16  = lane & 15;

  const bf16x8* Asv = (const bf16x8*)As;
  const bf16x8* Bsv = (const bf16x8*)Bs;

  f32x4 acc[4][4];
  #pragma unroll
  for (int mi = 0; mi < 4; ++mi)
    #pragma unroll
    for (int ni = 0; ni < 4; ++ni)
      acc[mi][ni] = (f32x4){0.f, 0.f, 0.f, 0.f};

  for (int k0 = 0; k0 < K; k0 += 32) {
    // stage + convert: 2 halves of 64 rows each
    *(bf16x8*)&As[srow * 32 + scol]        = cvt8(ap);
    *(bf16x8*)&As[(srow + 64) * 32 + scol] = cvt8(ap + 64 * K);
    *(bf16x8*)&Bs[srow * 32 + scol]        = cvt8(bp);
    *(bf16x8*)&Bs[(srow + 64) * 32 + scol] = cvt8(bp + 64 * K);
    ap += 32;
    bp += 32;
    __syncthreads();

    bf16x8 af[4], bfr[4];
    #pragma unroll
    for (int mi = 0; mi < 4; ++mi) af[mi]  = Asv[(wm + mi * 16 + l16) * 4 + quad];
    #pragma unroll
    for (int ni = 0; ni < 4; ++ni) bfr[ni] = Bsv[(wn + ni * 16 + l16) * 4 + quad];

    #pragma unroll
    for (int mi = 0; mi < 4; ++mi)
      #pragma unroll
      for (int ni = 0; ni < 4; ++ni)
        acc[mi][ni] = __builtin_amdgcn_mfma_f32_16x16x32_bf16(af[mi], bfr[ni], acc[mi][ni], 0, 0, 0);

    __syncthreads();
  }

  if (mat < 2) {
    // Q / K direct write.  C/D layout (m89/m91): n = l16, m = quad*4 + r
    __hip_bfloat16* outp = (mat == 0) ? Q : Kk;
    const float scale = (mat == 0) ? 0.03125f : 1.0f;   // 1/sqrt(1024) in Q
    #pragma unroll
    for (int mi = 0; mi < 4; ++mi) {
      #pragma unroll
      for (int r = 0; r < 4; ++r) {
        const long long row = tile_m + wm + mi * 16 + quad * 4 + r;
        #pragma unroll
        for (int ni = 0; ni < 4; ++ni) {
          const int col = coln0 + wn + ni * 16 + l16;
          outp[row * 1024 + col] = __float2bfloat16(acc[mi][ni][r] * scale);
        }
      }
    }
  } else {
    // V: lane's 4 r-values are seq-consecutive -> one 8B store per (mi,ni).
    const int b    = (int)(tile_m >> 11);
    const int seq0 = (int)(tile_m & 2047);
    #pragma unroll
    for (int mi = 0; mi < 4; ++mi) {
      const int seq = seq0 + wm + mi * 16 + quad * 4;
      #pragma unroll
      for (int ni = 0; ni < 4; ++ni) {
        const int d = coln0 + wn + ni * 16 + l16;
        union { ushort4 u; unsigned short s[4]; } pk;
        #pragma unroll
        for (int r = 0; r < 4; ++r)
          pk.s[r] = __bfloat16_as_ushort(__float2bfloat16(acc[mi][ni][r]));
        *(ushort4*)(Vt + ((long long)(b * 1024 + d)) * 2048 + seq) = pk.u;
      }
    }
  }
}

// ---------------- S = exp(Q K^T) + row-sum partials, BK=64 ----------------
__global__ __launch_bounds__(256)
void gemm_s_exp(const __hip_bfloat16* __restrict__ A,
                const __hip_bfloat16* __restrict__ B,
                __hip_bfloat16* __restrict__ Cout,
                float* __restrict__ part)
{
  __shared__ __align__(16) __hip_bfloat16 As[128 * 64];   // 16 KB
  __shared__ __align__(16) __hip_bfloat16 Bs[128 * 64];   // 16 KB

  const int K = 1024, N = 2048;
  const int bz = blockIdx.z;
  A += (long long)bz * 2048 * 1024;
  B += (long long)bz * 2048 * 1024;

  const long long tile_m = (long long)blockIdx.y * 128;
  const long long tile_n = (long long)blockIdx.x * 128;

  const int tid  = threadIdx.x;
  const int wid  = tid >> 6;
  const int lane = tid & 63;

  // BK=64 staging: lane i -> row wid*8 + i/8, col (i%8)*8; 4 passes of 32 rows
  const int srow = wid * 8 + (lane >> 3);
  const int scol = (lane & 7) * 8;

  const __hip_bfloat16* aptr = A + (tile_m + srow) * K + scol;
  const __hip_bfloat16* bptr = B + (tile_n + srow) * K + scol;
  char* la = (char*)As + (wid * 8) * 128;   // row stride 128 B
  char* lb = (char*)Bs + (wid * 8) * 128;

  const int wm   = (wid >> 1) * 64;
  const int wn   = (wid & 1) * 64;
  const int quad = lane >> 4;
  const int l16  = lane & 15;

  const bf16x8* Asv = (const bf16x8*)As;    // row = 8 x bf16x8
  const bf16x8* Bsv = (const bf16x8*)Bs;

  f32x4 acc[4][4];
  #pragma unroll
  for (int mi = 0; mi < 4; ++mi)
    #pragma unroll
    for (int ni = 0; ni < 4; ++ni)
      acc[mi][ni] = (f32x4){0.f, 0.f, 0.f, 0.f};

  for (int k0 = 0; k0 < K; k0 += 64) {
    #pragma unroll
    for (int p = 0; p < 4; ++p) {
      async_copy16(aptr + (long long)p * 32 * K, la + p * 32 * 128);
      async_copy16(bptr + (long long)p * 32 * K, lb + p * 32 * 128);
    }
    aptr += 64;
    bptr += 64;
    __syncthreads();

    #pragma unroll
    for (int kk = 0; kk < 2; ++kk) {
      bf16x8 af[4], bfr[4];
      #pragma unroll
      for (int mi = 0; mi < 4; ++mi) af[mi]  = Asv[(wm + mi * 16 + l16) * 8 + kk * 4 + quad];
      #pragma unroll
      for (int ni = 0; ni < 4; ++ni) bfr[ni] = Bsv[(wn + ni * 16 + l16) * 8 + kk * 4 + quad];
      #pragma unroll
      for (int mi = 0; mi < 4; ++mi)
        #pragma unroll
        for (int ni = 0; ni < 4; ++ni)
          acc[mi][ni] = __builtin_amdgcn_mfma_f32_16x16x32_bf16(af[mi], bfr[ni], acc[mi][ni], 0, 0, 0);
    }
    __syncthreads();
  }

  __hip_bfloat16* C = Cout + (long long)bz * 2048 * 2048;
  #pragma unroll
  for (int mi = 0; mi < 4; ++mi) {
    #pragma unroll
    for (int r = 0; r < 4; ++r) {
      const long long row = tile_m + wm + mi * 16 + quad * 4 + r;
      float s = 0.f;
      #pragma unroll
      for (int ni = 0; ni < 4; ++ni) {
        const float e = __expf(acc[mi][ni][r]);
        const __hip_bfloat16 h = __float2bfloat16(e);
        C[row * N + tile_n + wn + ni * 16 + l16] = h;
        s += __bfloat162float(h);
      }
      #pragma unroll
      for (int off = 1; off < 16; off <<= 1) s += __shfl_xor(s, off, 64);
      if (l16 == 0)
        part[((long long)bz * 2048 + row) * 32 + blockIdx.x * 2 + (wid & 1)] = s;
    }
  }
}

// ---------------- O = (P Vt^T) / rowsum, 128x64 tile, BK=64 ----------------
__global__ __launch_bounds__(256)
void gemm_pv(const __hip_bfloat16* __restrict__ A,     // expS [b][2048,2048]
             const __hip_bfloat16* __restrict__ B,     // Vt   [b][1024,2048]
             const float* __restrict__ part,           // [8192][32]
             float* __restrict__ Cout)                 // O    [b][2048,1024]
{
  __shared__ __align__(16) __hip_bfloat16 As[128 * 64];   // 16 KB
  __shared__ __align__(16) __hip_bfloat16 Bs[64 * 64];    // 8 KB
  __shared__ float rinv[128];

  const int K = 2048, N = 1024;
  const int bz = blockIdx.z;
  A += (long long)bz * 2048 * 2048;
  B += (long long)bz * 1024 * 2048;

  const long long tile_m = (long long)blockIdx.y * 128;
  const long long tile_n = (long long)blockIdx.x * 64;

  const int tid  = threadIdx.x;
  const int wid  = tid >> 6;
  const int lane = tid & 63;

  const int srow = wid * 8 + (lane >> 3);
  const int scol = (lane & 7) * 8;

  const __hip_bfloat16* aptr = A + (tile_m + srow) * K + scol;
  const __hip_bfloat16* bptr = B + (tile_n + srow) * K + scol;
  char* la = (char*)As + (wid * 8) * 128;
  char* lb = (char*)Bs + (wid * 8) * 128;

  const int wm   = (wid >> 1) * 64;
  const int wn   = (wid & 1) * 32;
  const int quad = lane >> 4;
  const int l16  = lane & 15;

  const bf16x8* Asv = (const bf16x8*)As;
  const bf16x8* Bsv = (const bf16x8*)Bs;

  f32x4 acc[4][2];
  #pragma unroll
  for (int mi = 0; mi < 4; ++mi)
    #pragma unroll
    for (int ni = 0; ni < 2; ++ni)
      acc[mi][ni] = (f32x4){0.f, 0.f, 0.f, 0.f};

  for (int k0 = 0; k0 < K; k0 += 64) {
    #pragma unroll
    for (int p = 0; p < 4; ++p)
      async_copy16(aptr + (long long)p * 32 * K, la + p * 32 * 128);
    #pragma unroll
    for (int p = 0; p < 2; ++p)
      async_copy16(bptr + (long long)p * 32 * K, lb + p * 32 * 128);
    aptr += 64;
    bptr += 64;
    __syncthreads();

    #pragma unroll
    for (int kk = 0; kk < 2; ++kk) {
      bf16x8 af[4], bfr[2];
      #pragma unroll
      for (int mi = 0; mi < 4; ++mi) af[mi]  = Asv[(wm + mi * 16 + l16) * 8 + kk * 4 + quad];
      #pragma unroll
      for (int ni = 0; ni < 2; ++ni) bfr[ni] = Bsv[(wn + ni * 16 + l16) * 8 + kk * 4 + quad];
      #pragma unroll
      for (int mi = 0; mi < 4; ++mi)
        #pragma unroll
        for (int ni = 0; ni < 2; ++ni)
          acc[mi][ni] = __builtin_amdgcn_mfma_f32_16x16x32_bf16(af[mi], bfr[ni], acc[mi][ni], 0, 0, 0);
    }
    __syncthreads();
  }

  // gather this tile's 128 row-sums (32 partials each), store reciprocal
  if (tid < 128) {
    const float4* pp = (const float4*)(part + ((long long)bz * 2048 + tile_m + tid) * 32);
    float s = 0.f;
    #pragma unroll
    for (int j = 0; j < 8; ++j) {
      const float4 f = pp[j];
      s += f.x + f.y + f.z + f.w;
    }
    rinv[tid] = 1.f / s;
  }
  __syncthreads();

  float* C = Cout + (long long)bz * 2048 * 1024;
  #pragma unroll
  for (int mi = 0; mi < 4; ++mi) {
    #pragma unroll
    for (int r = 0; r < 4; ++r) {
      const int rloc = wm + mi * 16 + quad * 4 + r;
      const float inv = rinv[rloc];
      const long long row = tile_m + rloc;
      #pragma unroll
      for (int ni = 0; ni < 2; ++ni) {
        const long long col = tile_n + wn + ni * 16 + l16;
        C[row * N + col] = acc[mi][ni][r] * inv;
      }
    }
  }
}

extern "C" void kernel_launch(void* const* d_in, const int* in_sizes, int n_in,
                              void* d_out, int out_size, void* d_ws, size_t ws_size,
                              hipStream_t stream)
{
  (void)in_sizes; (void)n_in; (void)out_size; (void)ws_size;

  const float* x  = (const float*)d_in[0];
  const float* Wq = (const float*)d_in[1];
  const float* Wk = (const float*)d_in[2];
  const float* Wv = (const float*)d_in[3];
  float* out = (float*)d_out;

  char* ws = (char*)d_ws;
  __hip_bfloat16* Q    = (__hip_bfloat16*)(ws);
  __hip_bfloat16* Kk   = (__hip_bfloat16*)(ws + (16LL << 20));
  __hip_bfloat16* Vt   = (__hip_bfloat16*)(ws + (32LL << 20));
  __hip_bfloat16* S    = (__hip_bfloat16*)(ws + (48LL << 20));
  float*          part = (float*)(ws + (80LL << 20));

  // fused cast + QKV projection; V lands transposed in Vt
  gemm_qkv<<<dim3(24, 64, 1), 256, 0, stream>>>(x, Wq, Wk, Wv, Q, Kk, Vt);

  // S = exp(Q K^T), row-sum partials
  gemm_s_exp<<<dim3(16, 16, 4), 256, 0, stream>>>(Q, Kk, S, part);

  // O = (P Vt^T) / rowsum -> fp32 d_out
  gemm_pv<<<dim3(16, 16, 4), 256, 0, stream>>>(S, Vt, part, out);
}

// Round 6
// 283.167 us; speedup vs baseline: 1.0369x; 1.0369x over previous
//
#include <hip/hip_runtime.h>
#include <hip/hip_bf16.h>
#include <stdint.h>

// ---------------------------------------------------------------------------
// Self-attention, single head, d=1024, seq=2048, batch=4, fp32 in/out.
// R6: revert R5's fused-cast staging (VALU staging cost 45 us: MfmaUtil 29->18,
//     FETCH 2x). cast_all + global_load_lds bf16 staging restored; BK=64
//     everywhere (R5 proved barrier-halving on s_exp/pv: ~20 us combined).
// Pipeline: cast_all | QKV = xb @ wcat^T (Q/32, V->Vt scatter) |
//           S = exp(QK^T) + rowsum partials | O = (P Vt^T)/rowsum
// Workspace (102 MiB): xb @ 0 (16; 1st MiB reused as part after qkv)
//   wcat @ 16 (6)  Q @ 22 (16)  K @ 38 (16)  Vt @ 54 (16)  S @ 70 (32)
// ---------------------------------------------------------------------------

typedef __attribute__((ext_vector_type(8))) short bf16x8;   // 8 bf16 = 4 VGPRs
typedef __attribute__((ext_vector_type(4))) float f32x4;

__device__ __forceinline__ void async_copy16(const void* g, void* l) {
  __builtin_amdgcn_global_load_lds(
      (__attribute__((address_space(1))) void*)(g),
      (__attribute__((address_space(3))) void*)(l),
      16, 0, 0);
}

// ---------------- fused QKV projection, BK=64 ----------------
// A = xb [8192,1024], B = wcat [3072,1024] (Wq | Wk | Wv rows)
// Q,K -> [8192,1024] bf16 (Q/32); V -> Vt [4][1024][2048] via 8B scatter.
__global__ __launch_bounds__(256)
void gemm_qkv(const __hip_bfloat16* __restrict__ A,
              const __hip_bfloat16* __restrict__ B,
              __hip_bfloat16* __restrict__ Q,
              __hip_bfloat16* __restrict__ Kk,
              __hip_bfloat16* __restrict__ Vt)
{
  __shared__ __align__(16) __hip_bfloat16 As[128 * 64];   // 16 KB
  __shared__ __align__(16) __hip_bfloat16 Bs[128 * 64];   // 16 KB

  const int K = 1024;
  const long long tile_m = (long long)blockIdx.y * 128;
  const long long tile_n = (long long)blockIdx.x * 128;

  const int tid  = threadIdx.x;
  const int wid  = tid >> 6;
  const int lane = tid & 63;

  // BK=64 staging: lane i -> row wid*8 + i/8, col (i%8)*8; 4 passes of 32 rows
  const int srow = wid * 8 + (lane >> 3);
  const int scol = (lane & 7) * 8;

  const __hip_bfloat16* aptr = A + (tile_m + srow) * K + scol;
  const __hip_bfloat16* bptr = B + (tile_n + srow) * K + scol;
  char* la = (char*)As + (wid * 8) * 128;   // row stride 128 B
  char* lb = (char*)Bs + (wid * 8) * 128;

  const int wm   = (wid >> 1) * 64;
  const int wn   = (wid & 1) * 64;
  const int quad = lane >> 4;
  const int l16  = lane & 15;

  const bf16x8* Asv = (const bf16x8*)As;    // row = 8 x bf16x8
  const bf16x8* Bsv = (const bf16x8*)Bs;

  f32x4 acc[4][4];
  #pragma unroll
  for (int mi = 0; mi < 4; ++mi)
    #pragma unroll
    for (int ni = 0; ni < 4; ++ni)
      acc[mi][ni] = (f32x4){0.f, 0.f, 0.f, 0.f};

  for (int k0 = 0; k0 < K; k0 += 64) {
    #pragma unroll
    for (int p = 0; p < 4; ++p) {
      async_copy16(aptr + (long long)p * 32 * K, la + p * 32 * 128);
      async_copy16(bptr + (long long)p * 32 * K, lb + p * 32 * 128);
    }
    aptr += 64;
    bptr += 64;
    __syncthreads();

    #pragma unroll
    for (int kk = 0; kk < 2; ++kk) {
      bf16x8 af[4], bfr[4];
      #pragma unroll
      for (int mi = 0; mi < 4; ++mi) af[mi]  = Asv[(wm + mi * 16 + l16) * 8 + kk * 4 + quad];
      #pragma unroll
      for (int ni = 0; ni < 4; ++ni) bfr[ni] = Bsv[(wn + ni * 16 + l16) * 8 + kk * 4 + quad];
      #pragma unroll
      for (int mi = 0; mi < 4; ++mi)
        #pragma unroll
        for (int ni = 0; ni < 4; ++ni)
          acc[mi][ni] = __builtin_amdgcn_mfma_f32_16x16x32_bf16(af[mi], bfr[ni], acc[mi][ni], 0, 0, 0);
    }
    __syncthreads();
  }

  const int mat = (int)(tile_n >> 10);
  if (mat < 2) {
    // Q / K direct write.  C/D layout (m89/m91): n = l16, m = quad*4 + r
    __hip_bfloat16* outp = (mat == 0) ? Q : Kk;
    const float scale = (mat == 0) ? 0.03125f : 1.0f;   // 1/sqrt(1024) in Q
    const int coln0 = (int)(tile_n & 1023);
    #pragma unroll
    for (int mi = 0; mi < 4; ++mi) {
      #pragma unroll
      for (int r = 0; r < 4; ++r) {
        const long long row = tile_m + wm + mi * 16 + quad * 4 + r;
        #pragma unroll
        for (int ni = 0; ni < 4; ++ni) {
          const int col = coln0 + wn + ni * 16 + l16;
          outp[row * 1024 + col] = __float2bfloat16(acc[mi][ni][r] * scale);
        }
      }
    }
  } else {
    // V: lane's 4 r-values are seq-consecutive -> one 8B store per (mi,ni).
    const int b    = (int)(tile_m >> 11);
    const int seq0 = (int)(tile_m & 2047);
    const int d0   = (int)(tile_n - 2048);
    #pragma unroll
    for (int mi = 0; mi < 4; ++mi) {
      const int seq = seq0 + wm + mi * 16 + quad * 4;
      #pragma unroll
      for (int ni = 0; ni < 4; ++ni) {
        const int d = d0 + wn + ni * 16 + l16;
        union { ushort4 u; unsigned short s[4]; } pk;
        #pragma unroll
        for (int r = 0; r < 4; ++r)
          pk.s[r] = __bfloat16_as_ushort(__float2bfloat16(acc[mi][ni][r]));
        *(ushort4*)(Vt + ((long long)(b * 1024 + d)) * 2048 + seq) = pk.u;
      }
    }
  }
}

// ---------------- S = exp(Q K^T) + row-sum partials, BK=64 ----------------
__global__ __launch_bounds__(256)
void gemm_s_exp(const __hip_bfloat16* __restrict__ A,
                const __hip_bfloat16* __restrict__ B,
                __hip_bfloat16* __restrict__ Cout,
                float* __restrict__ part)
{
  __shared__ __align__(16) __hip_bfloat16 As[128 * 64];   // 16 KB
  __shared__ __align__(16) __hip_bfloat16 Bs[128 * 64];   // 16 KB

  const int K = 1024, N = 2048;
  const int bz = blockIdx.z;
  A += (long long)bz * 2048 * 1024;
  B += (long long)bz * 2048 * 1024;

  const long long tile_m = (long long)blockIdx.y * 128;
  const long long tile_n = (long long)blockIdx.x * 128;

  const int tid  = threadIdx.x;
  const int wid  = tid >> 6;
  const int lane = tid & 63;

  const int srow = wid * 8 + (lane >> 3);
  const int scol = (lane & 7) * 8;

  const __hip_bfloat16* aptr = A + (tile_m + srow) * K + scol;
  const __hip_bfloat16* bptr = B + (tile_n + srow) * K + scol;
  char* la = (char*)As + (wid * 8) * 128;
  char* lb = (char*)Bs + (wid * 8) * 128;

  const int wm   = (wid >> 1) * 64;
  const int wn   = (wid & 1) * 64;
  const int quad = lane >> 4;
  const int l16  = lane & 15;

  const bf16x8* Asv = (const bf16x8*)As;
  const bf16x8* Bsv = (const bf16x8*)Bs;

  f32x4 acc[4][4];
  #pragma unroll
  for (int mi = 0; mi < 4; ++mi)
    #pragma unroll
    for (int ni = 0; ni < 4; ++ni)
      acc[mi][ni] = (f32x4){0.f, 0.f, 0.f, 0.f};

  for (int k0 = 0; k0 < K; k0 += 64) {
    #pragma unroll
    for (int p = 0; p < 4; ++p) {
      async_copy16(aptr + (long long)p * 32 * K, la + p * 32 * 128);
      async_copy16(bptr + (long long)p * 32 * K, lb + p * 32 * 128);
    }
    aptr += 64;
    bptr += 64;
    __syncthreads();

    #pragma unroll
    for (int kk = 0; kk < 2; ++kk) {
      bf16x8 af[4], bfr[4];
      #pragma unroll
      for (int mi = 0; mi < 4; ++mi) af[mi]  = Asv[(wm + mi * 16 + l16) * 8 + kk * 4 + quad];
      #pragma unroll
      for (int ni = 0; ni < 4; ++ni) bfr[ni] = Bsv[(wn + ni * 16 + l16) * 8 + kk * 4 + quad];
      #pragma unroll
      for (int mi = 0; mi < 4; ++mi)
        #pragma unroll
        for (int ni = 0; ni < 4; ++ni)
          acc[mi][ni] = __builtin_amdgcn_mfma_f32_16x16x32_bf16(af[mi], bfr[ni], acc[mi][ni], 0, 0, 0);
    }
    __syncthreads();
  }

  __hip_bfloat16* C = Cout + (long long)bz * 2048 * 2048;
  #pragma unroll
  for (int mi = 0; mi < 4; ++mi) {
    #pragma unroll
    for (int r = 0; r < 4; ++r) {
      const long long row = tile_m + wm + mi * 16 + quad * 4 + r;
      float s = 0.f;
      #pragma unroll
      for (int ni = 0; ni < 4; ++ni) {
        const float e = __expf(acc[mi][ni][r]);
        const __hip_bfloat16 h = __float2bfloat16(e);
        C[row * N + tile_n + wn + ni * 16 + l16] = h;
        s += __bfloat162float(h);
      }
      #pragma unroll
      for (int off = 1; off < 16; off <<= 1) s += __shfl_xor(s, off, 64);
      if (l16 == 0)
        part[((long long)bz * 2048 + row) * 32 + blockIdx.x * 2 + (wid & 1)] = s;
    }
  }
}

// ---------------- O = (P Vt^T) / rowsum, 128x64 tile, BK=64 ----------------
__global__ __launch_bounds__(256)
void gemm_pv(const __hip_bfloat16* __restrict__ A,     // expS [b][2048,2048]
             const __hip_bfloat16* __restrict__ B,     // Vt   [b][1024,2048]
             const float* __restrict__ part,           // [8192][32]
             float* __restrict__ Cout)                 // O    [b][2048,1024]
{
  __shared__ __align__(16) __hip_bfloat16 As[128 * 64];   // 16 KB
  __shared__ __align__(16) __hip_bfloat16 Bs[64 * 64];    // 8 KB
  __shared__ float rinv[128];

  const int K = 2048, N = 1024;
  const int bz = blockIdx.z;
  A += (long long)bz * 2048 * 2048;
  B += (long long)bz * 1024 * 2048;

  const long long tile_m = (long long)blockIdx.y * 128;
  const long long tile_n = (long long)blockIdx.x * 64;

  const int tid  = threadIdx.x;
  const int wid  = tid >> 6;
  const int lane = tid & 63;

  const int srow = wid * 8 + (lane >> 3);
  const int scol = (lane & 7) * 8;

  const __hip_bfloat16* aptr = A + (tile_m + srow) * K + scol;
  const __hip_bfloat16* bptr = B + (tile_n + srow) * K + scol;
  char* la = (char*)As + (wid * 8) * 128;
  char* lb = (char*)Bs + (wid * 8) * 128;

  const int wm   = (wid >> 1) * 64;
  const int wn   = (wid & 1) * 32;
  const int quad = lane >> 4;
  const int l16  = lane & 15;

  const bf16x8* Asv = (const bf16x8*)As;
  const bf16x8* Bsv = (const bf16x8*)Bs;

  f32x4 acc[4][2];
  #pragma unroll
  for (int mi = 0; mi < 4; ++mi)
    #pragma unroll
    for (int ni = 0; ni < 2; ++ni)
      acc[mi][ni] = (f32x4){0.f, 0.f, 0.f, 0.f};

  for (int k0 = 0; k0 < K; k0 += 64) {
    #pragma unroll
    for (int p = 0; p < 4; ++p)
      async_copy16(aptr + (long long)p * 32 * K, la + p * 32 * 128);
    #pragma unroll
    for (int p = 0; p < 2; ++p)
      async_copy16(bptr + (long long)p * 32 * K, lb + p * 32 * 128);
    aptr += 64;
    bptr += 64;
    __syncthreads();

    #pragma unroll
    for (int kk = 0; kk < 2; ++kk) {
      bf16x8 af[4], bfr[2];
      #pragma unroll
      for (int mi = 0; mi < 4; ++mi) af[mi]  = Asv[(wm + mi * 16 + l16) * 8 + kk * 4 + quad];
      #pragma unroll
      for (int ni = 0; ni < 2; ++ni) bfr[ni] = Bsv[(wn + ni * 16 + l16) * 8 + kk * 4 + quad];
      #pragma unroll
      for (int mi = 0; mi < 4; ++mi)
        #pragma unroll
        for (int ni = 0; ni < 2; ++ni)
          acc[mi][ni] = __builtin_amdgcn_mfma_f32_16x16x32_bf16(af[mi], bfr[ni], acc[mi][ni], 0, 0, 0);
    }
    __syncthreads();
  }

  // gather this tile's 128 row-sums (32 partials each), store reciprocal
  if (tid < 128) {
    const float4* pp = (const float4*)(part + ((long long)bz * 2048 + tile_m + tid) * 32);
    float s = 0.f;
    #pragma unroll
    for (int j = 0; j < 8; ++j) {
      const float4 f = pp[j];
      s += f.x + f.y + f.z + f.w;
    }
    rinv[tid] = 1.f / s;
  }
  __syncthreads();

  float* C = Cout + (long long)bz * 2048 * 1024;
  #pragma unroll
  for (int mi = 0; mi < 4; ++mi) {
    #pragma unroll
    for (int r = 0; r < 4; ++r) {
      const int rloc = wm + mi * 16 + quad * 4 + r;
      const float inv = rinv[rloc];
      const long long row = tile_m + rloc;
      #pragma unroll
      for (int ni = 0; ni < 2; ++ni) {
        const long long col = tile_n + wn + ni * 16 + l16;
        C[row * N + col] = acc[mi][ni][r] * inv;
      }
    }
  }
}

// ---------------- all casts in one dispatch ----------------
__global__ __launch_bounds__(256)
void cast_all(const float* __restrict__ x,
              const float* __restrict__ Wq, const float* __restrict__ Wk,
              const float* __restrict__ Wv,
              __hip_bfloat16* __restrict__ xb, __hip_bfloat16* __restrict__ wcat)
{
  const int bx = blockIdx.x;
  const float* src;
  __hip_bfloat16* dst;
  int i;
  if (bx < 8192) {                      // x: 2097152 float4s
    src = x; dst = xb; i = bx * 256 + threadIdx.x;
  } else {                              // weights: 262144 float4s each
    const int which = (bx - 8192) >> 10;
    src = (which == 0) ? Wq : (which == 1) ? Wk : Wv;
    dst = wcat + (long long)which * 1048576;
    i = ((bx - 8192) & 1023) * 256 + threadIdx.x;
  }
  const float4 f = ((const float4*)src)[i];
  union { ushort4 u; __hip_bfloat16 h[4]; } r;
  r.h[0] = __float2bfloat16(f.x);
  r.h[1] = __float2bfloat16(f.y);
  r.h[2] = __float2bfloat16(f.z);
  r.h[3] = __float2bfloat16(f.w);
  ((ushort4*)dst)[i] = r.u;
}

extern "C" void kernel_launch(void* const* d_in, const int* in_sizes, int n_in,
                              void* d_out, int out_size, void* d_ws, size_t ws_size,
                              hipStream_t stream)
{
  (void)in_sizes; (void)n_in; (void)out_size; (void)ws_size;

  const float* x  = (const float*)d_in[0];
  const float* Wq = (const float*)d_in[1];
  const float* Wk = (const float*)d_in[2];
  const float* Wv = (const float*)d_in[3];
  float* out = (float*)d_out;

  char* ws = (char*)d_ws;
  __hip_bfloat16* xb   = (__hip_bfloat16*)(ws);            // dead after qkv
  float*          part = (float*)(ws);                     // reuses xb region (1 MB)
  __hip_bfloat16* wcat = (__hip_bfloat16*)(ws + (16LL << 20));
  __hip_bfloat16* Q    = (__hip_bfloat16*)(ws + (22LL << 20));
  __hip_bfloat16* Kk   = (__hip_bfloat16*)(ws + (38LL << 20));
  __hip_bfloat16* Vt   = (__hip_bfloat16*)(ws + (54LL << 20));
  __hip_bfloat16* S    = (__hip_bfloat16*)(ws + (70LL << 20));

  cast_all<<<11264, 256, 0, stream>>>(x, Wq, Wk, Wv, xb, wcat);

  // fused QKV projection; V lands transposed in Vt via scattered stores
  gemm_qkv<<<dim3(24, 64, 1), 256, 0, stream>>>(xb, wcat, Q, Kk, Vt);

  // S = exp(Q K^T), row-sum partials -> part (overwrites dead xb)
  gemm_s_exp<<<dim3(16, 16, 4), 256, 0, stream>>>(Q, Kk, S, part);

  // O = (P Vt^T) / rowsum -> fp32 d_out
  gemm_pv<<<dim3(16, 16, 4), 256, 0, stream>>>(S, Vt, part, out);
}

// Round 7
// 250.490 us; speedup vs baseline: 1.1721x; 1.1305x over previous
//
#include <hip/hip_runtime.h>
#include <hip/hip_bf16.h>
#include <stdint.h>

// ---------------------------------------------------------------------------
// Self-attention, single head, d=1024, seq=2048, batch=4, fp32 in/out.
// R7: XOR-swizzled LDS layout. BK=64 row stride = 128 B = 32 banks, so the
//     naive layout gives 16-way conflicts on fragment ds_read_b128 (R6:
//     SQ_LDS_BANK_CONFLICT 6.3M -> 18.9M, qkv 72->91 us). global_load_lds
//     forces contiguous LDS dest, but the GLOBAL src addr is per-lane:
//     lane i fetches K-chunk (i&7)^(i>>3); reader indexes chunk k^(row&7).
//     -> 2 lanes/bank-group = free (m136).
// Pipeline: cast_all | QKV = xb @ wcat^T (Q/32, V->Vt scatter) |
//           S = exp(QK^T) + rowsum partials | O = (P Vt^T)/rowsum
// Workspace (102 MiB): xb @ 0 (16; 1st MiB reused as part after qkv)
//   wcat @ 16 (6)  Q @ 22 (16)  K @ 38 (16)  Vt @ 54 (16)  S @ 70 (32)
// ---------------------------------------------------------------------------

typedef __attribute__((ext_vector_type(8))) short bf16x8;   // 8 bf16 = 4 VGPRs
typedef __attribute__((ext_vector_type(4))) float f32x4;

__device__ __forceinline__ void async_copy16(const void* g, void* l) {
  __builtin_amdgcn_global_load_lds(
      (__attribute__((address_space(1))) void*)(g),
      (__attribute__((address_space(3))) void*)(l),
      16, 0, 0);
}

// ---------------- fused QKV projection, BK=64, swizzled ----------------
// A = xb [8192,1024], B = wcat [3072,1024] (Wq | Wk | Wv rows)
// Q,K -> [8192,1024] bf16 (Q/32); V -> Vt [4][1024][2048] via 8B scatter.
__global__ __launch_bounds__(256)
void gemm_qkv(const __hip_bfloat16* __restrict__ A,
              const __hip_bfloat16* __restrict__ B,
              __hip_bfloat16* __restrict__ Q,
              __hip_bfloat16* __restrict__ Kk,
              __hip_bfloat16* __restrict__ Vt)
{
  __shared__ __align__(16) __hip_bfloat16 As[128 * 64];   // 16 KB
  __shared__ __align__(16) __hip_bfloat16 Bs[128 * 64];   // 16 KB

  const int K = 1024;
  const long long tile_m = (long long)blockIdx.y * 128;
  const long long tile_n = (long long)blockIdx.x * 128;

  const int tid  = threadIdx.x;
  const int wid  = tid >> 6;
  const int lane = tid & 63;

  // staging: lane i -> row wid*8 + i/8 (+32/pass), K-chunk (i&7)^(i>>3)
  const int srow = wid * 8 + (lane >> 3);
  const int scol = (((lane & 7) ^ (lane >> 3))) * 8;   // swizzled source chunk

  const __hip_bfloat16* aptr = A + (tile_m + srow) * K + scol;
  const __hip_bfloat16* bptr = B + (tile_n + srow) * K + scol;
  char* la = (char*)As + (wid * 8) * 128;   // row stride 128 B
  char* lb = (char*)Bs + (wid * 8) * 128;

  const int wm   = (wid >> 1) * 64;
  const int wn   = (wid & 1) * 64;
  const int quad = lane >> 4;
  const int l16  = lane & 15;
  const int sw   = l16 & 7;                 // row&7 for all fragment rows

  const bf16x8* Asv = (const bf16x8*)As;    // row = 8 chunks of bf16x8
  const bf16x8* Bsv = (const bf16x8*)Bs;

  f32x4 acc[4][4];
  #pragma unroll
  for (int mi = 0; mi < 4; ++mi)
    #pragma unroll
    for (int ni = 0; ni < 4; ++ni)
      acc[mi][ni] = (f32x4){0.f, 0.f, 0.f, 0.f};

  for (int k0 = 0; k0 < K; k0 += 64) {
    #pragma unroll
    for (int p = 0; p < 4; ++p) {
      async_copy16(aptr + (long long)p * 32 * K, la + p * 32 * 128);
      async_copy16(bptr + (long long)p * 32 * K, lb + p * 32 * 128);
    }
    aptr += 64;
    bptr += 64;
    __syncthreads();

    #pragma unroll
    for (int kk = 0; kk < 2; ++kk) {
      bf16x8 af[4], bfr[4];
      const int ch = (kk * 4 + quad);
      #pragma unroll
      for (int mi = 0; mi < 4; ++mi) af[mi]  = Asv[(wm + mi * 16 + l16) * 8 + (ch ^ sw)];
      #pragma unroll
      for (int ni = 0; ni < 4; ++ni) bfr[ni] = Bsv[(wn + ni * 16 + l16) * 8 + (ch ^ sw)];
      #pragma unroll
      for (int mi = 0; mi < 4; ++mi)
        #pragma unroll
        for (int ni = 0; ni < 4; ++ni)
          acc[mi][ni] = __builtin_amdgcn_mfma_f32_16x16x32_bf16(af[mi], bfr[ni], acc[mi][ni], 0, 0, 0);
    }
    __syncthreads();
  }

  const int mat = (int)(tile_n >> 10);
  if (mat < 2) {
    // Q / K direct write.  C/D layout (m89/m91): n = l16, m = quad*4 + r
    __hip_bfloat16* outp = (mat == 0) ? Q : Kk;
    const float scale = (mat == 0) ? 0.03125f : 1.0f;   // 1/sqrt(1024) in Q
    const int coln0 = (int)(tile_n & 1023);
    #pragma unroll
    for (int mi = 0; mi < 4; ++mi) {
      #pragma unroll
      for (int r = 0; r < 4; ++r) {
        const long long row = tile_m + wm + mi * 16 + quad * 4 + r;
        #pragma unroll
        for (int ni = 0; ni < 4; ++ni) {
          const int col = coln0 + wn + ni * 16 + l16;
          outp[row * 1024 + col] = __float2bfloat16(acc[mi][ni][r] * scale);
        }
      }
    }
  } else {
    // V: lane's 4 r-values are seq-consecutive -> one 8B store per (mi,ni).
    const int b    = (int)(tile_m >> 11);
    const int seq0 = (int)(tile_m & 2047);
    const int d0   = (int)(tile_n - 2048);
    #pragma unroll
    for (int mi = 0; mi < 4; ++mi) {
      const int seq = seq0 + wm + mi * 16 + quad * 4;
      #pragma unroll
      for (int ni = 0; ni < 4; ++ni) {
        const int d = d0 + wn + ni * 16 + l16;
        union { ushort4 u; unsigned short s[4]; } pk;
        #pragma unroll
        for (int r = 0; r < 4; ++r)
          pk.s[r] = __bfloat16_as_ushort(__float2bfloat16(acc[mi][ni][r]));
        *(ushort4*)(Vt + ((long long)(b * 1024 + d)) * 2048 + seq) = pk.u;
      }
    }
  }
}

// ---------------- S = exp(Q K^T) + row-sum partials, BK=64, swizzled ----------------
__global__ __launch_bounds__(256)
void gemm_s_exp(const __hip_bfloat16* __restrict__ A,
                const __hip_bfloat16* __restrict__ B,
                __hip_bfloat16* __restrict__ Cout,
                float* __restrict__ part)
{
  __shared__ __align__(16) __hip_bfloat16 As[128 * 64];   // 16 KB
  __shared__ __align__(16) __hip_bfloat16 Bs[128 * 64];   // 16 KB

  const int K = 1024, N = 2048;
  const int bz = blockIdx.z;
  A += (long long)bz * 2048 * 1024;
  B += (long long)bz * 2048 * 1024;

  const long long tile_m = (long long)blockIdx.y * 128;
  const long long tile_n = (long long)blockIdx.x * 128;

  const int tid  = threadIdx.x;
  const int wid  = tid >> 6;
  const int lane = tid & 63;

  const int srow = wid * 8 + (lane >> 3);
  const int scol = (((lane & 7) ^ (lane >> 3))) * 8;

  const __hip_bfloat16* aptr = A + (tile_m + srow) * K + scol;
  const __hip_bfloat16* bptr = B + (tile_n + srow) * K + scol;
  char* la = (char*)As + (wid * 8) * 128;
  char* lb = (char*)Bs + (wid * 8) * 128;

  const int wm   = (wid >> 1) * 64;
  const int wn   = (wid & 1) * 64;
  const int quad = lane >> 4;
  const int l16  = lane & 15;
  const int sw   = l16 & 7;

  const bf16x8* Asv = (const bf16x8*)As;
  const bf16x8* Bsv = (const bf16x8*)Bs;

  f32x4 acc[4][4];
  #pragma unroll
  for (int mi = 0; mi < 4; ++mi)
    #pragma unroll
    for (int ni = 0; ni < 4; ++ni)
      acc[mi][ni] = (f32x4){0.f, 0.f, 0.f, 0.f};

  for (int k0 = 0; k0 < K; k0 += 64) {
    #pragma unroll
    for (int p = 0; p < 4; ++p) {
      async_copy16(aptr + (long long)p * 32 * K, la + p * 32 * 128);
      async_copy16(bptr + (long long)p * 32 * K, lb + p * 32 * 128);
    }
    aptr += 64;
    bptr += 64;
    __syncthreads();

    #pragma unroll
    for (int kk = 0; kk < 2; ++kk) {
      bf16x8 af[4], bfr[4];
      const int ch = (kk * 4 + quad);
      #pragma unroll
      for (int mi = 0; mi < 4; ++mi) af[mi]  = Asv[(wm + mi * 16 + l16) * 8 + (ch ^ sw)];
      #pragma unroll
      for (int ni = 0; ni < 4; ++ni) bfr[ni] = Bsv[(wn + ni * 16 + l16) * 8 + (ch ^ sw)];
      #pragma unroll
      for (int mi = 0; mi < 4; ++mi)
        #pragma unroll
        for (int ni = 0; ni < 4; ++ni)
          acc[mi][ni] = __builtin_amdgcn_mfma_f32_16x16x32_bf16(af[mi], bfr[ni], acc[mi][ni], 0, 0, 0);
    }
    __syncthreads();
  }

  __hip_bfloat16* C = Cout + (long long)bz * 2048 * 2048;
  #pragma unroll
  for (int mi = 0; mi < 4; ++mi) {
    #pragma unroll
    for (int r = 0; r < 4; ++r) {
      const long long row = tile_m + wm + mi * 16 + quad * 4 + r;
      float s = 0.f;
      #pragma unroll
      for (int ni = 0; ni < 4; ++ni) {
        const float e = __expf(acc[mi][ni][r]);
        const __hip_bfloat16 h = __float2bfloat16(e);
        C[row * N + tile_n + wn + ni * 16 + l16] = h;
        s += __bfloat162float(h);
      }
      #pragma unroll
      for (int off = 1; off < 16; off <<= 1) s += __shfl_xor(s, off, 64);
      if (l16 == 0)
        part[((long long)bz * 2048 + row) * 32 + blockIdx.x * 2 + (wid & 1)] = s;
    }
  }
}

// ---------------- O = (P Vt^T) / rowsum, 128x64 tile, BK=64, swizzled ----------------
__global__ __launch_bounds__(256)
void gemm_pv(const __hip_bfloat16* __restrict__ A,     // expS [b][2048,2048]
             const __hip_bfloat16* __restrict__ B,     // Vt   [b][1024,2048]
             const float* __restrict__ part,           // [8192][32]
             float* __restrict__ Cout)                 // O    [b][2048,1024]
{
  __shared__ __align__(16) __hip_bfloat16 As[128 * 64];   // 16 KB
  __shared__ __align__(16) __hip_bfloat16 Bs[64 * 64];    // 8 KB
  __shared__ float rinv[128];

  const int K = 2048, N = 1024;
  const int bz = blockIdx.z;
  A += (long long)bz * 2048 * 2048;
  B += (long long)bz * 1024 * 2048;

  const long long tile_m = (long long)blockIdx.y * 128;
  const long long tile_n = (long long)blockIdx.x * 64;

  const int tid  = threadIdx.x;
  const int wid  = tid >> 6;
  const int lane = tid & 63;

  const int srow = wid * 8 + (lane >> 3);
  const int scol = (((lane & 7) ^ (lane >> 3))) * 8;

  const __hip_bfloat16* aptr = A + (tile_m + srow) * K + scol;
  const __hip_bfloat16* bptr = B + (tile_n + srow) * K + scol;
  char* la = (char*)As + (wid * 8) * 128;
  char* lb = (char*)Bs + (wid * 8) * 128;

  const int wm   = (wid >> 1) * 64;
  const int wn   = (wid & 1) * 32;
  const int quad = lane >> 4;
  const int l16  = lane & 15;
  const int sw   = l16 & 7;

  const bf16x8* Asv = (const bf16x8*)As;
  const bf16x8* Bsv = (const bf16x8*)Bs;

  f32x4 acc[4][2];
  #pragma unroll
  for (int mi = 0; mi < 4; ++mi)
    #pragma unroll
    for (int ni = 0; ni < 2; ++ni)
      acc[mi][ni] = (f32x4){0.f, 0.f, 0.f, 0.f};

  for (int k0 = 0; k0 < K; k0 += 64) {
    #pragma unroll
    for (int p = 0; p < 4; ++p)
      async_copy16(aptr + (long long)p * 32 * K, la + p * 32 * 128);
    #pragma unroll
    for (int p = 0; p < 2; ++p)
      async_copy16(bptr + (long long)p * 32 * K, lb + p * 32 * 128);
    aptr += 64;
    bptr += 64;
    __syncthreads();

    #pragma unroll
    for (int kk = 0; kk < 2; ++kk) {
      bf16x8 af[4], bfr[2];
      const int ch = (kk * 4 + quad);
      #pragma unroll
      for (int mi = 0; mi < 4; ++mi) af[mi]  = Asv[(wm + mi * 16 + l16) * 8 + (ch ^ sw)];
      #pragma unroll
      for (int ni = 0; ni < 2; ++ni) bfr[ni] = Bsv[(wn + ni * 16 + l16) * 8 + (ch ^ sw)];
      #pragma unroll
      for (int mi = 0; mi < 4; ++mi)
        #pragma unroll
        for (int ni = 0; ni < 2; ++ni)
          acc[mi][ni] = __builtin_amdgcn_mfma_f32_16x16x32_bf16(af[mi], bfr[ni], acc[mi][ni], 0, 0, 0);
    }
    __syncthreads();
  }

  // gather this tile's 128 row-sums (32 partials each), store reciprocal
  if (tid < 128) {
    const float4* pp = (const float4*)(part + ((long long)bz * 2048 + tile_m + tid) * 32);
    float s = 0.f;
    #pragma unroll
    for (int j = 0; j < 8; ++j) {
      const float4 f = pp[j];
      s += f.x + f.y + f.z + f.w;
    }
    rinv[tid] = 1.f / s;
  }
  __syncthreads();

  float* C = Cout + (long long)bz * 2048 * 1024;
  #pragma unroll
  for (int mi = 0; mi < 4; ++mi) {
    #pragma unroll
    for (int r = 0; r < 4; ++r) {
      const int rloc = wm + mi * 16 + quad * 4 + r;
      const float inv = rinv[rloc];
      const long long row = tile_m + rloc;
      #pragma unroll
      for (int ni = 0; ni < 2; ++ni) {
        const long long col = tile_n + wn + ni * 16 + l16;
        C[row * N + col] = acc[mi][ni][r] * inv;
      }
    }
  }
}

// ---------------- all casts in one dispatch ----------------
__global__ __launch_bounds__(256)
void cast_all(const float* __restrict__ x,
              const float* __restrict__ Wq, const float* __restrict__ Wk,
              const float* __restrict__ Wv,
              __hip_bfloat16* __restrict__ xb, __hip_bfloat16* __restrict__ wcat)
{
  const int bx = blockIdx.x;
  const float* src;
  __hip_bfloat16* dst;
  int i;
  if (bx < 8192) {                      // x: 2097152 float4s
    src = x; dst = xb; i = bx * 256 + threadIdx.x;
  } else {                              // weights: 262144 float4s each
    const int which = (bx - 8192) >> 10;
    src = (which == 0) ? Wq : (which == 1) ? Wk : Wv;
    dst = wcat + (long long)which * 1048576;
    i = ((bx - 8192) & 1023) * 256 + threadIdx.x;
  }
  const float4 f = ((const float4*)src)[i];
  union { ushort4 u; __hip_bfloat16 h[4]; } r;
  r.h[0] = __float2bfloat16(f.x);
  r.h[1] = __float2bfloat16(f.y);
  r.h[2] = __float2bfloat16(f.z);
  r.h[3] = __float2bfloat16(f.w);
  ((ushort4*)dst)[i] = r.u;
}

extern "C" void kernel_launch(void* const* d_in, const int* in_sizes, int n_in,
                              void* d_out, int out_size, void* d_ws, size_t ws_size,
                              hipStream_t stream)
{
  (void)in_sizes; (void)n_in; (void)out_size; (void)ws_size;

  const float* x  = (const float*)d_in[0];
  const float* Wq = (const float*)d_in[1];
  const float* Wk = (const float*)d_in[2];
  const float* Wv = (const float*)d_in[3];
  float* out = (float*)d_out;

  char* ws = (char*)d_ws;
  __hip_bfloat16* xb   = (__hip_bfloat16*)(ws);            // dead after qkv
  float*          part = (float*)(ws);                     // reuses xb region (1 MB)
  __hip_bfloat16* wcat = (__hip_bfloat16*)(ws + (16LL << 20));
  __hip_bfloat16* Q    = (__hip_bfloat16*)(ws + (22LL << 20));
  __hip_bfloat16* Kk   = (__hip_bfloat16*)(ws + (38LL << 20));
  __hip_bfloat16* Vt   = (__hip_bfloat16*)(ws + (54LL << 20));
  __hip_bfloat16* S    = (__hip_bfloat16*)(ws + (70LL << 20));

  cast_all<<<11264, 256, 0, stream>>>(x, Wq, Wk, Wv, xb, wcat);

  // fused QKV projection; V lands transposed in Vt via scattered stores
  gemm_qkv<<<dim3(24, 64, 1), 256, 0, stream>>>(xb, wcat, Q, Kk, Vt);

  // S = exp(Q K^T), row-sum partials -> part (overwrites dead xb)
  gemm_s_exp<<<dim3(16, 16, 4), 256, 0, stream>>>(Q, Kk, S, part);

  // O = (P Vt^T) / rowsum -> fp32 d_out
  gemm_pv<<<dim3(16, 16, 4), 256, 0, stream>>>(S, Vt, part, out);
}